// Round 10
// baseline (272.941 us; speedup 1.0000x reference)
//
#include <hip/hip_runtime.h>

// Problem constants (from reference)
#define B_   16
#define OC_  10
#define N_   256
#define O_   2560   // OC_*N_
#define S_   64     // synapses
#define T_   512
#define KS_  48
#define TP_  561    // T + KS + 1
#define TT   24     // (fallback conv) time steps per thread
#define WROW 72     // (fallback conv) LDS row stride

// GEMM constants
#define XROWS 624           // xT rows: t' + 48 - j range, zero-padded
#define SCH    16           // neurons per block = one 64-B line
#define CPITCH 572          // codeW row pitch
#define KP     18           // keyB/codeB pitch (per t), Dquad=72dw=8 mod 32 -> 2-way

using i32x4 = __attribute__((ext_vector_type(4))) int;

// ===========================================================================
// prep_all (r8 version — REVERTED from r9): two segments only.  Round-9
// post-mortem: folding the 90 MB out-zeroing into prep_all left dirty zero
// lines in L2/L3 whose writeback drained DURING gemm_scan and evicted Bg
// (FETCH 13.6 -> 70 MB, WRITE +106 MB in gemm_scan's window, +43 us).  The
// serialized DMA memset (~19 us) is cheaper than the pollution.
//  - blocks [0, 512):    x [16][64][512] f32 -> xb [16][512][64] {0,1}  (x4)
//  - blocks [512, 2432): taps -> three signed base-256 digits (22-bit fixed
//    point) into Bg[oc][pos][row=d*16+ol][64], pos = 3*jm + jh  (x16)
// ===========================================================================
__global__ void prep_all(const float* __restrict__ x, const float* __restrict__ w,
                         unsigned char* __restrict__ xb, signed char* __restrict__ Bg) {
    if (blockIdx.x < 512) {
#pragma unroll
        for (int it = 0; it < 4; ++it) {
            int idx = blockIdx.x * 256 + threadIdx.x + it * 131072;  // < 524288
            int t = idx & 511;
            int bi = idx >> 9;
            int i = bi & 63, b = bi >> 6;
            xb[((size_t)(b * 512 + t) << 6) + i] = (x[idx] != 0.0f) ? 1 : 0;
        }
    } else {
        int base = (blockIdx.x - 512) * 256 + threadIdx.x;
#pragma unroll
        for (int it = 0; it < 16; ++it) {
            int idx = base + it * 491520;                  // < 7,864,320 exactly
            int i = idx & 63;
            int oj = idx >> 6;
            int j = oj % KS_, o = oj / KS_;
            float wv = w[(o << 6) + i];
            float rise = (float)j * 0.0625f;
            float leak = -((float)j - wv * 16.0f) * 0.03125f + wv;
            float kv   = fmaxf(0.0f, fminf(rise, leak));     // in [0,1]
            int q  = (int)lrintf(kv * 4194304.0f);           // kv * 2^22
            int d0 = ((q + 128) & 255) - 128;                // [-128,127]
            int q1 = (q - d0) >> 8;
            int d1 = ((q1 + 128) & 255) - 128;               // [-128,127]
            int d2 = (q1 - d1) >> 8;                         // [0,64]
            int oc = o >> 4, ol = o & 15;
            int jm = j & 15, jh = j >> 4;
            int pos = jm * 3 + jh;                           // triple-grouped
            size_t bse = (((size_t)(oc * KS_ + pos) * 48) + ol) * 64 + i;
            Bg[bse]            = (signed char)d0;            // digit 0
            Bg[bse + 16 * 64]  = (signed char)d1;            // digit 1
            Bg[bse + 32 * 64]  = (signed char)d2;            // digit 2
        }
    }
}

// ===========================================================================
// gemm_scan (r20 = r8 + TLOC0_EP, clean A/B): fused gemm+argmax+depression,
// sparse output via pre-zeroed d_out (hipMemsetAsync restored).
//  - keyB init'd once to -1e30 -> uniform branchless compare-update epilogue.
//  - For channels 1..4, tloc 0 is TLOC0_EP: prev channel's epilogue + acc
//    zeroing interleaved BETWEEN this channel's MFMA clusters (epilogue VALU
//    issues while the matrix pipe runs).  Final c=4 epilogue runs bare.
//  - Decision math bit-identical: exact i32 digit combine, single cvt->f32,
//    strict > argmax ascending channels, (best+16)>32 threshold.
//  - Core K-loop identical to the proven r14 config (144t x 16o/wave,
//    af-roll pipeline, barrier-free, 2 waves/SIMD).
// ===========================================================================
__global__ __launch_bounds__(512, 2) void gemm_scan(
    const unsigned char* __restrict__ xb,   // [16][512][64]
    const signed char*  __restrict__ Bg,    // [160][48][48][64]
    float* __restrict__ out)                // [B_][OC_][N_][TP_] (pre-zeroed)
{
    __shared__ __align__(16) unsigned char smem[143616];
    unsigned char* xT    = smem;                               // 39,936 (K-loop)
    unsigned char* codeW = smem;                               // 9,152 (alias, post-loop)
    float*         keyBB = (float*)(smem + 39936);             // 2 x 41,472
    unsigned char* codeBB = smem + 39936 + 82944;              // 2 x 10,368

    const int tid  = threadIdx.x;
    const int lane = tid & 63;
    const int wave = tid >> 6;          // 0..7
    const int tq   = wave >> 1;         // t-quarter 0..3
    const int chh  = wave & 1;          // channel half 0..1
    const int nc = blockIdx.x;          // 0..15 neuron chunk
    const int b  = blockIdx.y;          // 0..15
    const int lrow = lane & 15;
    const int quad = lane >> 4;
    const int tw = tq * 144;            // wave m-base (t)

    float*         keyB  = keyBB + chh * (576 * KP);
    unsigned char* codeB = codeBB + chh * (576 * KP);

    const size_t SL = (size_t)KS_ * 48 * 64;     // 147,456 B per oc-slice
    const signed char* Bcur = Bg + (size_t)(chh * 80 + nc) * SL
                            + lrow * 64 + quad * 16;

    // keyB init: each wave inits its OWN 36 slots/lane to -1e30 (first
    // channel's compare then always wins -> no init branch in the epilogue).
#pragma unroll
    for (int mi = 0; mi < 9; ++mi)
#pragma unroll
        for (int r = 0; r < 4; ++r)
            keyB[(tw + mi * 16 + quad * 4 + r) * KP + lrow] = -1.0e30f;

    // xT fill: zero ONLY pad rows (0..48, 561..623); data rows 49..560 <- x[b]
    for (int z = tid; z < 112 * 4; z += 512) {
        int zi = z >> 2, p = z & 3;
        int r = (zi < 49) ? zi : (561 + zi - 49);
        *(i32x4*)(xT + r * 64 + p * 16) = (i32x4){0, 0, 0, 0};
    }
    const unsigned char* xbb = xb + ((size_t)b << 15);   // 512*64 bytes
    for (int q = tid; q < 2048; q += 512) {              // 16-B chunks
        i32x4 v = *(const i32x4*)(xbb + q * 16);
        int t = q >> 2, p = q & 3;
        int r = 49 + t;
        *(i32x4*)(xT + r * 64 + ((p ^ ((r >> 1) & 3)) << 4)) = v;
    }

    i32x4 acc[9][3];
    i32x4 af[11], bfA[9], bfB[9];

    // B(ch-first, t=0) prefetch issued before the barrier (no xT dependency)
#pragma unroll
    for (int jh = 0; jh < 3; ++jh)
#pragma unroll
        for (int f = 0; f < 3; ++f)
            bfA[jh * 3 + f] = *(const i32x4*)(Bcur + jh * 3072 + f * 1024);

    __syncthreads();   // xT ready

    // af prologue for t=0
    {
        const int rb0 = tw + 16 + lrow;
        const int ca0 = ((quad ^ ((rb0 >> 1) & 3)) << 4);
#pragma unroll
        for (int k = 0; k < 11; ++k)
            af[k] = *(const i32x4*)(xT + (rb0 + k * 16) * 64 + ca0);
    }

#define MF(bfC, mi, jh, f)                                                    \
    acc[mi][f] = __builtin_amdgcn_mfma_i32_16x16x64_i8(                       \
        af[(mi) + 2 - (jh)], bfC[(jh) * 3 + (f)], acc[mi][f], 0, 0, 0)

#define PAIR(bfC, m0)                                                         \
    MF(bfC, m0, 0, 0); MF(bfC, m0, 0, 1); MF(bfC, m0, 0, 2);                  \
    MF(bfC, (m0)+1, 0, 0); MF(bfC, (m0)+1, 0, 1); MF(bfC, (m0)+1, 0, 2);      \
    MF(bfC, m0, 1, 0); MF(bfC, m0, 1, 1); MF(bfC, m0, 1, 2);                  \
    MF(bfC, (m0)+1, 1, 0); MF(bfC, (m0)+1, 1, 1); MF(bfC, (m0)+1, 1, 2);      \
    MF(bfC, m0, 2, 0); MF(bfC, m0, 2, 1); MF(bfC, m0, 2, 2);                  \
    MF(bfC, (m0)+1, 2, 0); MF(bfC, (m0)+1, 2, 1); MF(bfC, (m0)+1, 2, 2);

#define PAIR9(bfC)                                                            \
    MF(bfC, 8, 0, 0); MF(bfC, 8, 0, 1); MF(bfC, 8, 0, 2);                     \
    MF(bfC, 8, 1, 0); MF(bfC, 8, 1, 1); MF(bfC, 8, 1, 2);                     \
    MF(bfC, 8, 2, 0); MF(bfC, 8, 2, 1); MF(bfC, 8, 2, 2);

#define LDA_(row) (*(const i32x4*)(xT + (row) * 64 + coffN))
#define LDB_(BP, jh, f) (*(const i32x4*)((BP) + (tn3 + (jh)) * 3072 + (f) * 1024))

// epilogue element: exact i32 combine, one cvt->f32 (bit-identical to the
// double path), LDS compare-update (first-max-wins via strict >)
#define EPR(mi, r) {                                                          \
        int t_ = tw + (mi) * 16 + quad * 4 + (r);                             \
        int pq_i = acc[mi][0][r] + (acc[mi][1][r] << 8)                       \
                 + (acc[mi][2][r] << 16);                                     \
        float pq = (float)pq_i * 2.384185791015625e-7f;                       \
        int ix_ = t_ * KP + lrow;                                             \
        if (pq > keyB[ix_]) { keyB[ix_] = pq; codeB[ix_] = cvp; }             \
    }
#define EP(mi) EPR(mi, 0) EPR(mi, 1) EPR(mi, 2) EPR(mi, 3)

#define ZAC(mi) acc[mi][0] = (i32x4){0,0,0,0};                                \
                acc[mi][1] = (i32x4){0,0,0,0};                                \
                acc[mi][2] = (i32x4){0,0,0,0};

#define TLOC(T, bfC, bfN, BP) {                                               \
        const int rbn   = tw + 16 - (((T) + 1) & 15) + lrow;                  \
        const int coffN = ((quad ^ ((rbn >> 1) & 3)) << 4);                   \
        const int tn3   = (((T) + 1) & 15) * 3;                               \
        __builtin_amdgcn_s_setprio(1);                                        \
        PAIR(bfC, 0)                                                          \
        af[0] = LDA_(rbn);        af[1] = LDA_(rbn + 16);                     \
        bfN[0] = LDB_(BP, 0, 0); bfN[1] = LDB_(BP, 0, 1); bfN[2] = LDB_(BP, 0, 2); \
        PAIR(bfC, 2)                                                          \
        af[2] = LDA_(rbn + 32);   af[3] = LDA_(rbn + 48);                     \
        bfN[3] = LDB_(BP, 1, 0); bfN[4] = LDB_(BP, 1, 1); bfN[5] = LDB_(BP, 1, 2); \
        PAIR(bfC, 4)                                                          \
        af[4] = LDA_(rbn + 64);   af[5] = LDA_(rbn + 80);                     \
        bfN[6] = LDB_(BP, 2, 0); bfN[7] = LDB_(BP, 2, 1); bfN[8] = LDB_(BP, 2, 2); \
        PAIR(bfC, 6)                                                          \
        af[6] = LDA_(rbn + 96);   af[7] = LDA_(rbn + 112);                    \
        PAIR9(bfC)                                                            \
        af[8] = LDA_(rbn + 128);  af[9] = LDA_(rbn + 144);                    \
        af[10] = LDA_(rbn + 160);                                             \
        __builtin_amdgcn_s_setprio(0);                                        \
    }

// tloc 0 for channels >= 1: prev channel's epilogue + acc-zero interleaved
// between this channel's MFMA clusters.  EP(mi) reads final prev acc[mi];
// ZAC then zeroes it strictly before PAIR(mi) accumulates (SSA order).
// Validated for correctness in round 9 (absmax 0.0).
#define TLOC0_EP() {                                                          \
        const int rbn   = tw + 16 - 1 + lrow;                                 \
        const int coffN = ((quad ^ ((rbn >> 1) & 3)) << 4);                   \
        const int tn3   = 3;                                                  \
        const unsigned char cvp = (unsigned char)(chh * 5 + c);               \
        EP(0) EP(1) ZAC(0) ZAC(1)                                             \
        __builtin_amdgcn_s_setprio(1); PAIR(bfA, 0)                           \
        __builtin_amdgcn_s_setprio(0);                                        \
        af[0] = LDA_(rbn);        af[1] = LDA_(rbn + 16);                     \
        bfB[0] = LDB_(Bcur, 0, 0); bfB[1] = LDB_(Bcur, 0, 1);                 \
        bfB[2] = LDB_(Bcur, 0, 2);                                            \
        EP(2) EP(3) ZAC(2) ZAC(3)                                             \
        __builtin_amdgcn_s_setprio(1); PAIR(bfA, 2)                           \
        __builtin_amdgcn_s_setprio(0);                                        \
        af[2] = LDA_(rbn + 32);   af[3] = LDA_(rbn + 48);                     \
        bfB[3] = LDB_(Bcur, 1, 0); bfB[4] = LDB_(Bcur, 1, 1);                 \
        bfB[5] = LDB_(Bcur, 1, 2);                                            \
        EP(4) EP(5) ZAC(4) ZAC(5)                                             \
        __builtin_amdgcn_s_setprio(1); PAIR(bfA, 4)                           \
        __builtin_amdgcn_s_setprio(0);                                        \
        af[4] = LDA_(rbn + 64);   af[5] = LDA_(rbn + 80);                     \
        bfB[6] = LDB_(Bcur, 2, 0); bfB[7] = LDB_(Bcur, 2, 1);                 \
        bfB[8] = LDB_(Bcur, 2, 2);                                            \
        EP(6) EP(7) ZAC(6) ZAC(7)                                             \
        __builtin_amdgcn_s_setprio(1); PAIR(bfA, 6)                           \
        __builtin_amdgcn_s_setprio(0);                                        \
        af[6] = LDA_(rbn + 96);   af[7] = LDA_(rbn + 112);                    \
        EP(8) ZAC(8)                                                          \
        __builtin_amdgcn_s_setprio(1); PAIR9(bfA)                             \
        __builtin_amdgcn_s_setprio(0);                                        \
        af[8] = LDA_(rbn + 128);  af[9] = LDA_(rbn + 144);                    \
        af[10] = LDA_(rbn + 160);                                             \
    }

    for (int c = 0; c < 5; ++c) {
        const signed char* Bnxt = (c == 4) ? Bcur : (Bcur + 16 * SL);

        if (c == 0) {
#pragma unroll
            for (int mi = 0; mi < 9; ++mi)
#pragma unroll
                for (int f = 0; f < 3; ++f)
                    acc[mi][f] = (i32x4){0, 0, 0, 0};
            TLOC(0, bfA, bfB, Bcur)
        } else {
            TLOC0_EP()
        }
        TLOC(1, bfB, bfA, Bcur)
        for (int tp = 1; tp < 7; ++tp) {
            TLOC(2 * tp,     bfA, bfB, Bcur)
            TLOC(2 * tp + 1, bfB, bfA, Bcur)
        }
        TLOC(14, bfA, bfB, Bcur)
        TLOC(15, bfB, bfA, Bnxt)    // prefetch next channel's t=0 into bfA
        Bcur = Bnxt;
    }

    // final epilogue: channel c=4 of this half
    {
        const unsigned char cvp = (unsigned char)(chh * 5 + 5);
        EP(0) EP(1) EP(2) EP(3) EP(4) EP(5) EP(6) EP(7) EP(8)
    }

#undef MF
#undef PAIR
#undef PAIR9
#undef LDA_
#undef LDB_
#undef EPR
#undef EP
#undef ZAC
#undef TLOC
#undef TLOC0_EP

    __syncthreads();   // all halves' argmax buffers complete; xT dead

    // merge halves -> codeW[nl][t] (aliases xT region); half 0 preferred on
    // ties (lower channel = first max, matching the reference scan)
    for (int ix = tid; ix < 576 * 16; ix += 512) {
        int t = ix >> 4, nl = ix & 15;
        if (t >= TP_) continue;
        int ip = t * KP + nl;
        float f0 = keyBB[ip];
        float f1 = keyBB[576 * KP + ip];
        float best = f0;
        unsigned char cd = codeBB[ip];
        if (f1 > f0) { best = f1; cd = codeBB[576 * KP + ip]; }
        codeW[nl * CPITCH + t] = ((best + 16.0f) > 32.0f) ? cd : (unsigned char)0;
    }
    __syncthreads();

    // ballot depression walk — wave handles neurons {wave, wave+8};
    // winner lane scatters 1.0f directly into the pre-zeroed output.
    {
        const int ln = tid & 63;
        float* ob = out + (((size_t)b * OC_) * N_ + nc * SCH) * TP_;
        for (int nsel = wave; nsel < SCH; nsel += 8) {
            const unsigned char* cp = &codeW[nsel * CPITCH];
            int t = 0;
            while (t < TP_) {
                int tt = t + ln;
                unsigned char v = (tt < TP_) ? cp[tt] : (unsigned char)0;
                unsigned long long mask = __ballot(v != 0);
                if (mask == 0ULL) { t += 64; continue; }
                int k = (int)__builtin_ctzll(mask);
                if (ln == k)
                    ob[((size_t)(v - 1) * N_ + nsel) * TP_ + (t + k)] = 1.0f;
                t += k + KS_;
            }
        }
    }
}

// ===========================================================================
// FALLBACK (round-1 direct conv) — only if ws_size too small
// ===========================================================================
__global__ void transpose_w(const float* __restrict__ w, float* __restrict__ wT) {
    int idx = blockIdx.x * 256 + threadIdx.x;
    if (idx >= O_ * S_) return;
    int o = idx >> 6, i = idx & 63;
    wT[i * O_ + o] = w[idx];
}

__global__ __launch_bounds__(256) void conv_kernel(
    const float* __restrict__ x, const float* __restrict__ wT,
    float* __restrict__ pot)
{
    const int b  = blockIdx.y;
    const int t0 = blockIdx.z * TT;
    const int o  = blockIdx.x * 256 + threadIdx.x;

    __shared__ __align__(16) float xsh[S_][WROW];
    for (int idx = threadIdx.x; idx < S_ * WROW; idx += 256) {
        int i = idx / WROW, m = idx - i * WROW;
        int t = t0 - KS_ + m;
        float v = 0.0f;
        if (t >= 0 && t < T_) v = x[(b * S_ + i) * T_ + t];
        xsh[i][m] = v;
    }
    __syncthreads();

    float acch[TT], accl[TT];
#pragma unroll
    for (int tl = 0; tl < TT; ++tl) { acch[tl] = 0.0f; accl[tl] = 0.0f; }

    for (int i = 0; i < S_; ++i) {
        float xw[WROW];
#pragma unroll
        for (int w4 = 0; w4 < WROW / 4; ++w4) {
            const float4 v = *reinterpret_cast<const float4*>(&xsh[i][w4 * 4]);
            xw[w4 * 4 + 0] = v.x; xw[w4 * 4 + 1] = v.y;
            xw[w4 * 4 + 2] = v.z; xw[w4 * 4 + 3] = v.w;
        }
        const float wv = wT[i * O_ + o];
#pragma unroll
        for (int j = 1; j < KS_; ++j) {
            float rise = (float)j * 0.0625f;
            float leak = -((float)j - wv * 16.0f) * 0.03125f + wv;
            float kv   = fmaxf(0.0f, fminf(rise, leak));
            float khi  = rintf(kv * 4096.0f) * 2.44140625e-4f;
            float klo  = kv - khi;
#pragma unroll
            for (int tl = 0; tl < TT; ++tl) {
                float xv = xw[tl + (KS_ - 1) - j];
                acch[tl] = fmaf(xv, khi, acch[tl]);
                accl[tl] = fmaf(xv, klo, accl[tl]);
            }
        }
    }
#pragma unroll
    for (int tl = 0; tl < TT; ++tl) {
        int t = t0 + tl;
        if (t < TP_) pot[((size_t)b * TP_ + t) * O_ + o] = acch[tl] + accl[tl];
    }
}

__global__ void scan_prep(const float* __restrict__ pot, unsigned char* __restrict__ code) {
    int idx = blockIdx.x * 256 + threadIdx.x;
    if (idx >= B_ * TP_ * N_) return;
    int n  = idx & (N_ - 1);
    int bt = idx >> 8;
    const float* p = pot + (size_t)bt * O_ + n;
    float best = p[0]; int bo = 0;
#pragma unroll
    for (int oc = 1; oc < OC_; ++oc) {
        float v = p[oc * N_];
        if (v > best) { best = v; bo = oc; }
    }
    code[idx] = ((best + 16.0f) > 32.0f) ? (unsigned char)(bo + 1) : (unsigned char)0;
}

__global__ void scan_run(const unsigned char* __restrict__ code, float* __restrict__ out) {
    int idx = blockIdx.x * 256 + threadIdx.x;
    if (idx >= B_ * N_) return;
    int b = idx >> 8, n = idx & 255;
    const unsigned char* c = code + (size_t)b * TP_ * N_ + n;
    int t = 0;
    while (t < TP_) {
        unsigned char buf[KS_];
#pragma unroll
        for (int k = 0; k < KS_; ++k) {
            int tt = t + k;
            buf[k] = (tt < TP_) ? c[(size_t)tt * N_] : (unsigned char)0;
        }
        int adv = KS_;
#pragma unroll
        for (int k = 0; k < KS_; ++k) {
            if (buf[k]) {
                out[(((size_t)b * OC_ + (buf[k] - 1)) * N_ + n) * TP_ + (t + k)] = 1.0f;
                adv = k + KS_;
                break;
            }
        }
        t += adv;
    }
}

// ===========================================================================
extern "C" void kernel_launch(void* const* d_in, const int* in_sizes, int n_in,
                              void* d_out, int out_size, void* d_ws, size_t ws_size,
                              hipStream_t stream) {
    const float* x = (const float*)d_in[0];   // [16][1][64][512] binary
    const float* w = (const float*)d_in[1];   // [2560][64]
    float* out = (float*)d_out;               // [16][10][256][561]

    char* ws = (char*)d_ws;
    const size_t szX = (size_t)B_ * T_ * S_;                    //     524,288
    const size_t szB = (size_t)160 * KS_ * 48 * 64;             //  23,592,960
    const size_t need = szX + szB;                              //  ~24.1 MB

    if (ws_size >= need) {
        unsigned char* xb  = (unsigned char*)ws;
        signed char* Bg    = (signed char*)(ws + szX);

        hipMemsetAsync(d_out, 0, (size_t)out_size * sizeof(float), stream);
        prep_all<<<2432, 256, 0, stream>>>(x, w, xb, Bg);
        gemm_scan<<<dim3(16, 16), 512, 0, stream>>>(xb, Bg, out);
    } else {
        // fallback: round-1 direct conv (needs ~95 MB)
        size_t pot_bytes  = (size_t)B_ * TP_ * O_ * sizeof(float);
        size_t code_bytes = (size_t)B_ * TP_ * N_;
        float* pot = (float*)ws;
        unsigned char* code = (unsigned char*)(ws + pot_bytes);
        float* wT = (float*)(ws + pot_bytes + code_bytes);

        hipMemsetAsync(d_out, 0, (size_t)out_size * sizeof(float), stream);
        transpose_w<<<(O_ * S_ + 255) / 256, 256, 0, stream>>>(w, wT);
        conv_kernel<<<dim3(O_ / 256, B_, (TP_ + TT - 1) / TT), 256, 0, stream>>>(x, wT, pot);
        scan_prep<<<(B_ * TP_ * N_ + 255) / 256, 256, 0, stream>>>(pot, code);
        scan_run<<<(B_ * N_ + 255) / 256, 256, 0, stream>>>(code, out);
    }
}

// Round 11
// 227.861 us; speedup vs baseline: 1.1978x; 1.1978x over previous
//
#include <hip/hip_runtime.h>

// Problem constants (from reference)
#define B_   16
#define OC_  10
#define N_   256
#define O_   2560   // OC_*N_
#define S_   64     // synapses
#define T_   512
#define KS_  48
#define TP_  561    // T + KS + 1
#define TT   24     // (fallback conv) time steps per thread
#define WROW 72     // (fallback conv) LDS row stride

// GEMM constants
#define XROWS 624           // xT rows: t' + 48 - j range, zero-padded
#define SCH    16           // neurons per block = one 64-B line
#define CPITCH 572          // codeW row pitch
#define KP     18           // keyB/codeB pitch (per t), Dquad=72dw=8 mod 32 -> 2-way

#define OUTF4  5744640      // out size in float4 (16*10*256*561/4)

using i32x4 = __attribute__((ext_vector_type(4))) int;

// ===========================================================================
// prep_all: one dispatch, grid-strided, THREE segments (all concurrent).
// r10 post-mortem: r9-vs-r10 A/B proved the zero-fill segment is NOT the
// pollution source (gemm counters identical either way; totals favor the
// fused zero-fill by ~6 us since it overlaps instead of serializing).
//  - blocks [0, 512):     x [16][64][512] f32 -> xb [16][512][64] {0,1} (x4)
//  - blocks [512, 2432):  taps -> three signed base-256 digits (22-bit fixed
//                         point) into Bg[oc][pos][row=d*16+ol][64]     (x16)
//  - blocks [2432, 5312): zero d_out (replaces serialized hipMemsetAsync)
// ===========================================================================
__global__ void prep_all(const float* __restrict__ x, const float* __restrict__ w,
                         unsigned char* __restrict__ xb, signed char* __restrict__ Bg,
                         float* __restrict__ outz) {
    if (blockIdx.x < 512) {
#pragma unroll
        for (int it = 0; it < 4; ++it) {
            int idx = blockIdx.x * 256 + threadIdx.x + it * 131072;  // < 524288
            int t = idx & 511;
            int bi = idx >> 9;
            int i = bi & 63, b = bi >> 6;
            xb[((size_t)(b * 512 + t) << 6) + i] = (x[idx] != 0.0f) ? 1 : 0;
        }
    } else if (blockIdx.x < 2432) {
        int base = (blockIdx.x - 512) * 256 + threadIdx.x;
#pragma unroll
        for (int it = 0; it < 16; ++it) {
            int idx = base + it * 491520;                  // < 7,864,320 exactly
            int i = idx & 63;
            int oj = idx >> 6;
            int j = oj % KS_, o = oj / KS_;
            float wv = w[(o << 6) + i];
            float rise = (float)j * 0.0625f;
            float leak = -((float)j - wv * 16.0f) * 0.03125f + wv;
            float kv   = fmaxf(0.0f, fminf(rise, leak));     // in [0,1]
            int q  = (int)lrintf(kv * 4194304.0f);           // kv * 2^22
            int d0 = ((q + 128) & 255) - 128;                // [-128,127]
            int q1 = (q - d0) >> 8;
            int d1 = ((q1 + 128) & 255) - 128;               // [-128,127]
            int d2 = (q1 - d1) >> 8;                         // [0,64]
            int oc = o >> 4, ol = o & 15;
            int jm = j & 15, jh = j >> 4;
            int pos = jm * 3 + jh;                           // triple-grouped
            size_t bse = (((size_t)(oc * KS_ + pos) * 48) + ol) * 64 + i;
            Bg[bse]            = (signed char)d0;            // digit 0
            Bg[bse + 16 * 64]  = (signed char)d1;            // digit 1
            Bg[bse + 32 * 64]  = (signed char)d2;            // digit 2
        }
    } else {
        i32x4* o4 = (i32x4*)outz;
        int base = (blockIdx.x - 2432) * 256 + threadIdx.x;
#pragma unroll
        for (int it = 0; it < 8; ++it) {
            int idx = base + it * 737280;
            if (idx < OUTF4) o4[idx] = (i32x4){0, 0, 0, 0};
        }
    }
}

// ===========================================================================
// gemm_scan (r21 = EXACT r8 kernel, proven 134.6 us / FETCH 13.6 MB):
// fused gemm+argmax+depression, sparse output into pre-zeroed d_out.
// r10 post-mortem: TLOC0_EP (r9/r10's epilogue interleave) caused ~105 MB of
// scratch spill traffic (WRITE 106 MB, FETCH +56 MB inside gemm's window,
// +41 us) — live ranges of acc/af/bf stretched past the register budget.
// REVERTED to the serial per-channel epilogue, which r8 measured at only
// ~7 us exposure.  Core K-loop = proven r14 config (144t x 16o/wave,
// af-roll pipeline, barrier-free, 2 waves/SIMD).  Decision math exact:
// i32 digit combine, single cvt->f32 (bit-identical to the double path),
// strict > argmax ascending channels, (best+16)>32 threshold.
// ===========================================================================
__global__ __launch_bounds__(512, 2) void gemm_scan(
    const unsigned char* __restrict__ xb,   // [16][512][64]
    const signed char*  __restrict__ Bg,    // [160][48][48][64]
    float* __restrict__ out)                // [B_][OC_][N_][TP_] (pre-zeroed)
{
    __shared__ __align__(16) unsigned char smem[143616];
    unsigned char* xT    = smem;                               // 39,936 (K-loop)
    unsigned char* codeW = smem;                               // 9,152 (alias, post-loop)
    float*         keyBB = (float*)(smem + 39936);             // 2 x 41,472
    unsigned char* codeBB = smem + 39936 + 82944;              // 2 x 10,368

    const int tid  = threadIdx.x;
    const int lane = tid & 63;
    const int wave = tid >> 6;          // 0..7
    const int tq   = wave >> 1;         // t-quarter 0..3
    const int chh  = wave & 1;          // channel half 0..1
    const int nc = blockIdx.x;          // 0..15 neuron chunk
    const int b  = blockIdx.y;          // 0..15
    const int lrow = lane & 15;
    const int quad = lane >> 4;
    const int tw = tq * 144;            // wave m-base (t)

    float*         keyB  = keyBB + chh * (576 * KP);
    unsigned char* codeB = codeBB + chh * (576 * KP);

    const size_t SL = (size_t)KS_ * 48 * 64;     // 147,456 B per oc-slice
    const signed char* Bcur = Bg + (size_t)(chh * 80 + nc) * SL
                            + lrow * 64 + quad * 16;

    // xT fill: zero ONLY pad rows (0..48, 561..623); data rows 49..560 <- x[b]
    for (int z = tid; z < 112 * 4; z += 512) {
        int zi = z >> 2, p = z & 3;
        int r = (zi < 49) ? zi : (561 + zi - 49);
        *(i32x4*)(xT + r * 64 + p * 16) = (i32x4){0, 0, 0, 0};
    }
    const unsigned char* xbb = xb + ((size_t)b << 15);   // 512*64 bytes
    for (int q = tid; q < 2048; q += 512) {              // 16-B chunks
        i32x4 v = *(const i32x4*)(xbb + q * 16);
        int t = q >> 2, p = q & 3;
        int r = 49 + t;
        *(i32x4*)(xT + r * 64 + ((p ^ ((r >> 1) & 3)) << 4)) = v;
    }

    i32x4 acc[9][3];
    i32x4 af[11], bfA[9], bfB[9];

    // B(ch-first, t=0) prefetch issued before the barrier (no xT dependency)
#pragma unroll
    for (int jh = 0; jh < 3; ++jh)
#pragma unroll
        for (int f = 0; f < 3; ++f)
            bfA[jh * 3 + f] = *(const i32x4*)(Bcur + jh * 3072 + f * 1024);

    __syncthreads();   // xT ready

    // af prologue for t=0
    {
        const int rb0 = tw + 16 + lrow;
        const int ca0 = ((quad ^ ((rb0 >> 1) & 3)) << 4);
#pragma unroll
        for (int k = 0; k < 11; ++k)
            af[k] = *(const i32x4*)(xT + (rb0 + k * 16) * 64 + ca0);
    }

#define MF(bfC, mi, jh, f)                                                    \
    acc[mi][f] = __builtin_amdgcn_mfma_i32_16x16x64_i8(                       \
        af[(mi) + 2 - (jh)], bfC[(jh) * 3 + (f)], acc[mi][f], 0, 0, 0)

#define PAIR(bfC, m0)                                                         \
    MF(bfC, m0, 0, 0); MF(bfC, m0, 0, 1); MF(bfC, m0, 0, 2);                  \
    MF(bfC, (m0)+1, 0, 0); MF(bfC, (m0)+1, 0, 1); MF(bfC, (m0)+1, 0, 2);      \
    MF(bfC, m0, 1, 0); MF(bfC, m0, 1, 1); MF(bfC, m0, 1, 2);                  \
    MF(bfC, (m0)+1, 1, 0); MF(bfC, (m0)+1, 1, 1); MF(bfC, (m0)+1, 1, 2);      \
    MF(bfC, m0, 2, 0); MF(bfC, m0, 2, 1); MF(bfC, m0, 2, 2);                  \
    MF(bfC, (m0)+1, 2, 0); MF(bfC, (m0)+1, 2, 1); MF(bfC, (m0)+1, 2, 2);

#define PAIR9(bfC)                                                            \
    MF(bfC, 8, 0, 0); MF(bfC, 8, 0, 1); MF(bfC, 8, 0, 2);                     \
    MF(bfC, 8, 1, 0); MF(bfC, 8, 1, 1); MF(bfC, 8, 1, 2);                     \
    MF(bfC, 8, 2, 0); MF(bfC, 8, 2, 1); MF(bfC, 8, 2, 2);

#define LDA_(row) (*(const i32x4*)(xT + (row) * 64 + coffN))
#define LDB_(BP, jh, f) (*(const i32x4*)((BP) + (tn3 + (jh)) * 3072 + (f) * 1024))

#define TLOC(T, bfC, bfN, BP) {                                               \
        const int rbn   = tw + 16 - (((T) + 1) & 15) + lrow;                  \
        const int coffN = ((quad ^ ((rbn >> 1) & 3)) << 4);                   \
        const int tn3   = (((T) + 1) & 15) * 3;                               \
        __builtin_amdgcn_s_setprio(1);                                        \
        PAIR(bfC, 0)                                                          \
        af[0] = LDA_(rbn);        af[1] = LDA_(rbn + 16);                     \
        bfN[0] = LDB_(BP, 0, 0); bfN[1] = LDB_(BP, 0, 1); bfN[2] = LDB_(BP, 0, 2); \
        PAIR(bfC, 2)                                                          \
        af[2] = LDA_(rbn + 32);   af[3] = LDA_(rbn + 48);                     \
        bfN[3] = LDB_(BP, 1, 0); bfN[4] = LDB_(BP, 1, 1); bfN[5] = LDB_(BP, 1, 2); \
        PAIR(bfC, 4)                                                          \
        af[4] = LDA_(rbn + 64);   af[5] = LDA_(rbn + 80);                     \
        bfN[6] = LDB_(BP, 2, 0); bfN[7] = LDB_(BP, 2, 1); bfN[8] = LDB_(BP, 2, 2); \
        PAIR(bfC, 6)                                                          \
        af[6] = LDA_(rbn + 96);   af[7] = LDA_(rbn + 112);                    \
        PAIR9(bfC)                                                            \
        af[8] = LDA_(rbn + 128);  af[9] = LDA_(rbn + 144);                    \
        af[10] = LDA_(rbn + 160);                                             \
        __builtin_amdgcn_s_setprio(0);                                        \
    }

    for (int c = 0; c < 5; ++c) {
        const signed char* Bnxt = (c == 4) ? Bcur : (Bcur + 16 * SL);

#pragma unroll
        for (int mi = 0; mi < 9; ++mi)
#pragma unroll
            for (int f = 0; f < 3; ++f)
                acc[mi][f] = (i32x4){0, 0, 0, 0};

        for (int tp = 0; tp < 7; ++tp) {
            TLOC(2 * tp,     bfA, bfB, Bcur)
            TLOC(2 * tp + 1, bfB, bfA, Bcur)
        }
        TLOC(14, bfA, bfB, Bcur)
        TLOC(15, bfB, bfA, Bnxt)    // prefetch next channel's t=0 into bfA

        // per-channel epilogue (serial, r8-proven ~7 us total): i32 digit
        // combine (exact), one cvt->f32, LDS compare-update argmax.
        {
            const unsigned char cv = (unsigned char)(chh * 5 + c + 1);
#pragma unroll
            for (int mi = 0; mi < 9; ++mi) {
#pragma unroll
                for (int r = 0; r < 4; ++r) {
                    int t = tw + mi * 16 + quad * 4 + r;     // < 576
                    int pq_i = acc[mi][0][r] + (acc[mi][1][r] << 8)
                             + (acc[mi][2][r] << 16);
                    float pq = (float)pq_i * 2.384185791015625e-7f; // *2^-22
                    int ix = t * KP + lrow;
                    if (c == 0) {
                        keyB[ix] = pq; codeB[ix] = cv;
                    } else if (pq > keyB[ix]) {   // strict >: first max wins
                        keyB[ix] = pq; codeB[ix] = cv;
                    }
                }
            }
        }
        Bcur = Bnxt;
    }

#undef MF
#undef PAIR
#undef PAIR9
#undef LDA_
#undef LDB_
#undef TLOC

    __syncthreads();   // all halves' argmax buffers complete; xT dead

    // merge halves -> codeW[nl][t] (aliases xT region); half 0 preferred on
    // ties (lower channel = first max, matching the reference scan)
    for (int ix = tid; ix < 576 * 16; ix += 512) {
        int t = ix >> 4, nl = ix & 15;
        if (t >= TP_) continue;
        int ip = t * KP + nl;
        float f0 = keyBB[ip];
        float f1 = keyBB[576 * KP + ip];
        float best = f0;
        unsigned char cd = codeBB[ip];
        if (f1 > f0) { best = f1; cd = codeBB[576 * KP + ip]; }
        codeW[nl * CPITCH + t] = ((best + 16.0f) > 32.0f) ? cd : (unsigned char)0;
    }
    __syncthreads();

    // ballot depression walk — wave handles neurons {wave, wave+8};
    // winner lane scatters 1.0f directly into the pre-zeroed output.
    {
        const int ln = tid & 63;
        float* ob = out + (((size_t)b * OC_) * N_ + nc * SCH) * TP_;
        for (int nsel = wave; nsel < SCH; nsel += 8) {
            const unsigned char* cp = &codeW[nsel * CPITCH];
            int t = 0;
            while (t < TP_) {
                int tt = t + ln;
                unsigned char v = (tt < TP_) ? cp[tt] : (unsigned char)0;
                unsigned long long mask = __ballot(v != 0);
                if (mask == 0ULL) { t += 64; continue; }
                int k = (int)__builtin_ctzll(mask);
                if (ln == k)
                    ob[((size_t)(v - 1) * N_ + nsel) * TP_ + (t + k)] = 1.0f;
                t += k + KS_;
            }
        }
    }
}

// ===========================================================================
// FALLBACK (round-1 direct conv) — only if ws_size too small
// ===========================================================================
__global__ void transpose_w(const float* __restrict__ w, float* __restrict__ wT) {
    int idx = blockIdx.x * 256 + threadIdx.x;
    if (idx >= O_ * S_) return;
    int o = idx >> 6, i = idx & 63;
    wT[i * O_ + o] = w[idx];
}

__global__ __launch_bounds__(256) void conv_kernel(
    const float* __restrict__ x, const float* __restrict__ wT,
    float* __restrict__ pot)
{
    const int b  = blockIdx.y;
    const int t0 = blockIdx.z * TT;
    const int o  = blockIdx.x * 256 + threadIdx.x;

    __shared__ __align__(16) float xsh[S_][WROW];
    for (int idx = threadIdx.x; idx < S_ * WROW; idx += 256) {
        int i = idx / WROW, m = idx - i * WROW;
        int t = t0 - KS_ + m;
        float v = 0.0f;
        if (t >= 0 && t < T_) v = x[(b * S_ + i) * T_ + t];
        xsh[i][m] = v;
    }
    __syncthreads();

    float acch[TT], accl[TT];
#pragma unroll
    for (int tl = 0; tl < TT; ++tl) { acch[tl] = 0.0f; accl[tl] = 0.0f; }

    for (int i = 0; i < S_; ++i) {
        float xw[WROW];
#pragma unroll
        for (int w4 = 0; w4 < WROW / 4; ++w4) {
            const float4 v = *reinterpret_cast<const float4*>(&xsh[i][w4 * 4]);
            xw[w4 * 4 + 0] = v.x; xw[w4 * 4 + 1] = v.y;
            xw[w4 * 4 + 2] = v.z; xw[w4 * 4 + 3] = v.w;
        }
        const float wv = wT[i * O_ + o];
#pragma unroll
        for (int j = 1; j < KS_; ++j) {
            float rise = (float)j * 0.0625f;
            float leak = -((float)j - wv * 16.0f) * 0.03125f + wv;
            float kv   = fmaxf(0.0f, fminf(rise, leak));
            float khi  = rintf(kv * 4096.0f) * 2.44140625e-4f;
            float klo  = kv - khi;
#pragma unroll
            for (int tl = 0; tl < TT; ++tl) {
                float xv = xw[tl + (KS_ - 1) - j];
                acch[tl] = fmaf(xv, khi, acch[tl]);
                accl[tl] = fmaf(xv, klo, accl[tl]);
            }
        }
    }
#pragma unroll
    for (int tl = 0; tl < TT; ++tl) {
        int t = t0 + tl;
        if (t < TP_) pot[((size_t)b * TP_ + t) * O_ + o] = acch[tl] + accl[tl];
    }
}

__global__ void scan_prep(const float* __restrict__ pot, unsigned char* __restrict__ code) {
    int idx = blockIdx.x * 256 + threadIdx.x;
    if (idx >= B_ * TP_ * N_) return;
    int n  = idx & (N_ - 1);
    int bt = idx >> 8;
    const float* p = pot + (size_t)bt * O_ + n;
    float best = p[0]; int bo = 0;
#pragma unroll
    for (int oc = 1; oc < OC_; ++oc) {
        float v = p[oc * N_];
        if (v > best) { best = v; bo = oc; }
    }
    code[idx] = ((best + 16.0f) > 32.0f) ? (unsigned char)(bo + 1) : (unsigned char)0;
}

__global__ void scan_run(const unsigned char* __restrict__ code, float* __restrict__ out) {
    int idx = blockIdx.x * 256 + threadIdx.x;
    if (idx >= B_ * N_) return;
    int b = idx >> 8, n = idx & 255;
    const unsigned char* c = code + (size_t)b * TP_ * N_ + n;
    int t = 0;
    while (t < TP_) {
        unsigned char buf[KS_];
#pragma unroll
        for (int k = 0; k < KS_; ++k) {
            int tt = t + k;
            buf[k] = (tt < TP_) ? c[(size_t)tt * N_] : (unsigned char)0;
        }
        int adv = KS_;
#pragma unroll
        for (int k = 0; k < KS_; ++k) {
            if (buf[k]) {
                out[(((size_t)b * OC_ + (buf[k] - 1)) * N_ + n) * TP_ + (t + k)] = 1.0f;
                adv = k + KS_;
                break;
            }
        }
        t += adv;
    }
}

// ===========================================================================
extern "C" void kernel_launch(void* const* d_in, const int* in_sizes, int n_in,
                              void* d_out, int out_size, void* d_ws, size_t ws_size,
                              hipStream_t stream) {
    const float* x = (const float*)d_in[0];   // [16][1][64][512] binary
    const float* w = (const float*)d_in[1];   // [2560][64]
    float* out = (float*)d_out;               // [16][10][256][561]

    char* ws = (char*)d_ws;
    const size_t szX = (size_t)B_ * T_ * S_;                    //     524,288
    const size_t szB = (size_t)160 * KS_ * 48 * 64;             //  23,592,960
    const size_t need = szX + szB;                              //  ~24.1 MB

    if (ws_size >= need) {
        unsigned char* xb  = (unsigned char*)ws;
        signed char* Bg    = (signed char*)(ws + szX);

        prep_all<<<5312, 256, 0, stream>>>(x, w, xb, Bg, out);
        gemm_scan<<<dim3(16, 16), 512, 0, stream>>>(xb, Bg, out);
    } else {
        // fallback: round-1 direct conv (needs ~95 MB)
        size_t pot_bytes  = (size_t)B_ * TP_ * O_ * sizeof(float);
        size_t code_bytes = (size_t)B_ * TP_ * N_;
        float* pot = (float*)ws;
        unsigned char* code = (unsigned char*)(ws + pot_bytes);
        float* wT = (float*)(ws + pot_bytes + code_bytes);

        hipMemsetAsync(d_out, 0, (size_t)out_size * sizeof(float), stream);
        transpose_w<<<(O_ * S_ + 255) / 256, 256, 0, stream>>>(w, wT);
        conv_kernel<<<dim3(O_ / 256, B_, (TP_ + TT - 1) / TT), 256, 0, stream>>>(x, wT, pot);
        scan_prep<<<(B_ * TP_ * N_ + 255) / 256, 256, 0, stream>>>(pot, code);
        scan_run<<<(B_ * N_ + 255) / 256, 256, 0, stream>>>(code, out);
    }
}